// Round 13
// baseline (125.377 us; speedup 1.0000x reference)
//
#include <hip/hip_runtime.h>
#include <math.h>

#define L_SEQ 192
#define H_DIM 768
#define B_SZ  8
#define NPAIR (L_SEQ * (L_SEQ + 1) / 2)   // 18528
#define MROWS (B_SZ * L_SEQ)              // 1536
#define NCOLS (2 * H_DIM)                 // 1536 (D columns: [A | C])
#define NTILE 24
#define NTRI  (NTILE * (NTILE + 1) / 2)    // 300

#define SEQ_ELEMS (MROWS * H_DIM)          // 1,179,648
#define W_ELEMS   (H_DIM * NCOLS)          // 1,179,648
#define D_BYTES   ((size_t)MROWS * NCOLS * 4)
#define WS_NEED_FULL (D_BYTES + 4 * (size_t)SEQ_ELEMS * 2)   // 18.9 MB

typedef short  bf16x8  __attribute__((ext_vector_type(8)));
typedef float  f32x4   __attribute__((ext_vector_type(4)));
typedef unsigned short u16x4 __attribute__((ext_vector_type(4)));
typedef unsigned short u16x8 __attribute__((ext_vector_type(8)));

__device__ __forceinline__ void tri_decode(int p, int Lq, int& io, int& jo) {
    float tl = 2.0f * Lq + 1.0f;
    int i = (int)((tl - sqrtf(tl * tl - 8.0f * (float)p)) * 0.5f);
    if (i < 0) i = 0;
    if (i > Lq - 1) i = Lq - 1;
    while (i > 0 && i * (2 * Lq - i + 1) / 2 > p) --i;
    while (i < Lq - 1 && (i + 1) * (2 * Lq - i) / 2 <= p) ++i;
    io = i;
    jo = i + (p - i * (2 * Lq - i + 1) / 2);
}

struct HL { unsigned short h, l; };

__device__ __forceinline__ HL split_bf16(float x) {
    HL r;
    unsigned u  = __float_as_uint(x);
    unsigned rh = u + 0x7FFFu + ((u >> 16) & 1u);
    r.h = (unsigned short)(rh >> 16);
    float hf = __uint_as_float((unsigned)r.h << 16);
    float res = x - hf;
    unsigned u2 = __float_as_uint(res);
    unsigned rl = u2 + 0x7FFFu + ((u2 >> 16) & 1u);
    r.l = (unsigned short)(rl >> 16);
    return r;
}

__device__ __forceinline__ float fast_tanh(float x) {
    float e = __builtin_amdgcn_exp2f(x * 2.885390081777927f);
    return 1.0f - 2.0f * __builtin_amdgcn_rcpf(e + 1.0f);
}

// ---------------------------------------------------------------------------
// Presplit: seq -> SH/SL, W -> WH/WL (hi/lo bf16), one float4 per thread.
// ---------------------------------------------------------------------------
__global__ __launch_bounds__(256) void presplit_kernel(
    const float* __restrict__ seq, const float* __restrict__ W,
    unsigned short* __restrict__ SH, unsigned short* __restrict__ SL,
    unsigned short* __restrict__ WH, unsigned short* __restrict__ WL)
{
    int idx = blockIdx.x * 256 + threadIdx.x;
    const int NSEQ4 = SEQ_ELEMS / 4;
    const float4* src;
    u16x4 *dh, *dl;
    if (idx < NSEQ4) {
        src = reinterpret_cast<const float4*>(seq) + idx;
        dh = reinterpret_cast<u16x4*>(SH) + idx;
        dl = reinterpret_cast<u16x4*>(SL) + idx;
    } else {
        int k = idx - NSEQ4;
        src = reinterpret_cast<const float4*>(W) + k;
        dh = reinterpret_cast<u16x4*>(WH) + k;
        dl = reinterpret_cast<u16x4*>(WL) + k;
    }
    float4 v = *src;
    HL sx = split_bf16(v.x), sy = split_bf16(v.y);
    HL sz = split_bf16(v.z), sw = split_bf16(v.w);
    *dh = (u16x4){sx.h, sy.h, sz.h, sw.h};
    *dl = (u16x4){sx.l, sy.l, sz.l, sw.l};
}

// ---------------------------------------------------------------------------
// 128x128-tile GEMM from pre-split bf16: 12x12 = 144 blocks, 4 waves (2x2),
// each wave 64x64 = 4x4 frags of 16x16x32; 3 MFMAs per frag pair (hh+hl+lh).
// vs the 64x64 version: 48 MFMAs per 16 frag-reads per wave-k-step (2x fewer
// LDS reads per FLOP), 2x less staging per FLOP, half the L2 fetch.
// LDS 40KB single-buffered (dbuf proven null in r11).
// ---------------------------------------------------------------------------
#define LDSP 40

__global__ __launch_bounds__(256) void gemm_bf16_128_kernel(
    const unsigned short* __restrict__ SH, const unsigned short* __restrict__ SL,
    const unsigned short* __restrict__ WH, const unsigned short* __restrict__ WL,
    float* __restrict__ D)
{
    __shared__ unsigned short Ah[128 * LDSP], Al[128 * LDSP];
    __shared__ unsigned short Bh[128 * LDSP], Bl[128 * LDSP];

    const int t    = threadIdx.x;
    const int bn0  = blockIdx.x * 128;
    const int bm0  = blockIdx.y * 128;
    const int side = (bn0 >= H_DIM) ? 1 : 0;     // uniform (768 % 128 == 0)
    const int wrow0 = bn0 - side * H_DIM;
    const int kofs  = side * H_DIM;

    const int lane = t & 63;
    const int wave = t >> 6;
    const int wr   = wave >> 1, wc = wave & 1;   // 2x2 wave grid
    const int l15  = lane & 15;
    const int kc   = (lane >> 4) * 8;

    // staging: row = t>>1 (0..127), k-half = (t&1)*16 shorts (32B/thread/array)
    const int sr = t >> 1;
    const int sk = (t & 1) * 16;

    const unsigned short* srcA_h = SH + (size_t)(bm0 + sr) * H_DIM + sk;
    const unsigned short* srcA_l = SL + (size_t)(bm0 + sr) * H_DIM + sk;
    const unsigned short* srcB_h = WH + (size_t)(wrow0 + sr) * NCOLS + kofs + sk;
    const unsigned short* srcB_l = WL + (size_t)(wrow0 + sr) * NCOLS + kofs + sk;
    const int wofs = sr * LDSP + sk;

    f32x4 acc[4][4];
    #pragma unroll
    for (int a = 0; a < 4; ++a)
        #pragma unroll
        for (int b = 0; b < 4; ++b) acc[a][b] = (f32x4){0.f, 0.f, 0.f, 0.f};

    // prefetch regs: 2 u16x8 per array (32B)
    u16x8 rah0 = *reinterpret_cast<const u16x8*>(srcA_h);
    u16x8 rah1 = *reinterpret_cast<const u16x8*>(srcA_h + 8);
    u16x8 ral0 = *reinterpret_cast<const u16x8*>(srcA_l);
    u16x8 ral1 = *reinterpret_cast<const u16x8*>(srcA_l + 8);
    u16x8 rbh0 = *reinterpret_cast<const u16x8*>(srcB_h);
    u16x8 rbh1 = *reinterpret_cast<const u16x8*>(srcB_h + 8);
    u16x8 rbl0 = *reinterpret_cast<const u16x8*>(srcB_l);
    u16x8 rbl1 = *reinterpret_cast<const u16x8*>(srcB_l + 8);

    #pragma unroll 1
    for (int k0 = 0; k0 < H_DIM; k0 += 32) {
        // write current tile to LDS
        *reinterpret_cast<u16x8*>(Ah + wofs)     = rah0;
        *reinterpret_cast<u16x8*>(Ah + wofs + 8) = rah1;
        *reinterpret_cast<u16x8*>(Al + wofs)     = ral0;
        *reinterpret_cast<u16x8*>(Al + wofs + 8) = ral1;
        *reinterpret_cast<u16x8*>(Bh + wofs)     = rbh0;
        *reinterpret_cast<u16x8*>(Bh + wofs + 8) = rbh1;
        *reinterpret_cast<u16x8*>(Bl + wofs)     = rbl0;
        *reinterpret_cast<u16x8*>(Bl + wofs + 8) = rbl1;
        // prefetch next tile into regs (overlaps with barrier + frag reads)
        if (k0 + 32 < H_DIM) {
            rah0 = *reinterpret_cast<const u16x8*>(srcA_h + k0 + 32);
            rah1 = *reinterpret_cast<const u16x8*>(srcA_h + k0 + 40);
            ral0 = *reinterpret_cast<const u16x8*>(srcA_l + k0 + 32);
            ral1 = *reinterpret_cast<const u16x8*>(srcA_l + k0 + 40);
            rbh0 = *reinterpret_cast<const u16x8*>(srcB_h + k0 + 32);
            rbh1 = *reinterpret_cast<const u16x8*>(srcB_h + k0 + 40);
            rbl0 = *reinterpret_cast<const u16x8*>(srcB_l + k0 + 32);
            rbl1 = *reinterpret_cast<const u16x8*>(srcB_l + k0 + 40);
        }
        __syncthreads();

        bf16x8 ah[4], al[4], bh[4], bl[4];
        #pragma unroll
        for (int mi = 0; mi < 4; ++mi) {
            int row = wr * 64 + mi * 16 + l15;
            ah[mi] = *reinterpret_cast<const bf16x8*>(Ah + row * LDSP + kc);
            al[mi] = *reinterpret_cast<const bf16x8*>(Al + row * LDSP + kc);
        }
        #pragma unroll
        for (int ni = 0; ni < 4; ++ni) {
            int row = wc * 64 + ni * 16 + l15;
            bh[ni] = *reinterpret_cast<const bf16x8*>(Bh + row * LDSP + kc);
            bl[ni] = *reinterpret_cast<const bf16x8*>(Bl + row * LDSP + kc);
        }

        #pragma unroll
        for (int mi = 0; mi < 4; ++mi)
            #pragma unroll
            for (int ni = 0; ni < 4; ++ni) {
                acc[mi][ni] = __builtin_amdgcn_mfma_f32_16x16x32_bf16(ah[mi], bh[ni], acc[mi][ni], 0, 0, 0);
                acc[mi][ni] = __builtin_amdgcn_mfma_f32_16x16x32_bf16(ah[mi], bl[ni], acc[mi][ni], 0, 0, 0);
                acc[mi][ni] = __builtin_amdgcn_mfma_f32_16x16x32_bf16(al[mi], bh[ni], acc[mi][ni], 0, 0, 0);
            }
        __syncthreads();
    }

    // epilogue: C/D layout col = lane&15, row = (lane>>4)*4 + r
    #pragma unroll
    for (int mi = 0; mi < 4; ++mi)
        #pragma unroll
        for (int ni = 0; ni < 4; ++ni) {
            int row0 = bm0 + wr * 64 + mi * 16 + (lane >> 4) * 4;
            int col  = bn0 + wc * 64 + ni * 16 + l15;
            #pragma unroll
            for (int r = 0; r < 4; ++r)
                D[(size_t)(row0 + r) * NCOLS + col] = acc[mi][ni][r];
        }
}

// ---------------------------------------------------------------------------
// Tiled combine (round-9 winner, structural ceiling ~94us): one block =
// 8x8 (i,j) pair tile, one b; 16 indep loads, 64 indep stores, plain stores.
// ---------------------------------------------------------------------------
__global__ __launch_bounds__(192) void combine_tile_kernel(
    const float* __restrict__ D, const float* __restrict__ bias,
    float* __restrict__ out)
{
    const int b = blockIdx.y;
    int it, jt;
    tri_decode(blockIdx.x, NTILE, it, jt);

    const int h = threadIdx.x * 4;
    const f32x4 bb = *reinterpret_cast<const f32x4*>(bias + h);
    const float* Dbase = D + (size_t)b * L_SEQ * NCOLS;

    f32x4 Ar[8], Cr[8];
    #pragma unroll
    for (int r = 0; r < 8; ++r)
        Ar[r] = *reinterpret_cast<const f32x4*>(Dbase + (size_t)(it * 8 + r) * NCOLS + h) + bb;
    #pragma unroll
    for (int r = 0; r < 8; ++r)
        Cr[r] = *reinterpret_cast<const f32x4*>(Dbase + (size_t)(jt * 8 + r) * NCOLS + H_DIM + h);

    const int diag = (it == jt);

    #pragma unroll
    for (int di = 0; di < 8; ++di) {
        const int i = it * 8 + di;
        const int prow = i * (2 * L_SEQ - i + 1) / 2 - i;   // p = prow + j
        float* orow = out + ((size_t)b * NPAIR + prow) * H_DIM + h;
        #pragma unroll
        for (int dj = 0; dj < 8; ++dj) {
            if (diag && dj < di) continue;
            const int j = jt * 8 + dj;
            f32x4 s = Ar[di] + Cr[dj];
            f32x4 o;
            o.x = fast_tanh(s.x); o.y = fast_tanh(s.y);
            o.z = fast_tanh(s.z); o.w = fast_tanh(s.w);
            *reinterpret_cast<f32x4*>(orow + (size_t)j * H_DIM) = o;
        }
    }
}

// ---------------------------------------------------------------------------
// Fallbacks (middle: in-kernel split + LDS GEMM; last: naive einsum)
// ---------------------------------------------------------------------------
__global__ __launch_bounds__(256) void gemm_mfma64_kernel(
    const float* __restrict__ seq, const float* __restrict__ W,
    float* __restrict__ D)
{
    __shared__ unsigned short Ahs[64 * LDSP], Als[64 * LDSP];
    __shared__ unsigned short Bhs[64 * LDSP], Bls[64 * LDSP];
    const int t    = threadIdx.x;
    const int bn0  = blockIdx.x * 64;
    const int bm0  = blockIdx.y * 64;
    const int side = (bn0 >= H_DIM) ? 1 : 0;
    const int wrow0 = bn0 - side * H_DIM;
    const int kofs  = side * H_DIM;
    const int lane = t & 63;
    const int wave = t >> 6;
    const int wr   = wave >> 1, wc = wave & 1;
    const int l15  = lane & 15;
    const int kc   = (lane >> 4) * 8;
    const int sr = t >> 2;
    const int sk = (t & 3) * 8;

    f32x4 acc[2][2];
    #pragma unroll
    for (int a = 0; a < 2; ++a)
        #pragma unroll
        for (int b = 0; b < 2; ++b) acc[a][b] = (f32x4){0.f, 0.f, 0.f, 0.f};

    for (int k0 = 0; k0 < H_DIM; k0 += 32) {
        {
            const float* src = seq + (size_t)(bm0 + sr) * H_DIM + k0 + sk;
            #pragma unroll
            for (int c = 0; c < 2; ++c) {
                float4 v = *reinterpret_cast<const float4*>(src + c * 4);
                HL sx = split_bf16(v.x), sy = split_bf16(v.y);
                HL sz = split_bf16(v.z), sw = split_bf16(v.w);
                *reinterpret_cast<u16x4*>(Ahs + sr * LDSP + sk + c * 4) = (u16x4){sx.h, sy.h, sz.h, sw.h};
                *reinterpret_cast<u16x4*>(Als + sr * LDSP + sk + c * 4) = (u16x4){sx.l, sy.l, sz.l, sw.l};
            }
        }
        {
            const float* src = W + (size_t)(wrow0 + sr) * NCOLS + kofs + k0 + sk;
            #pragma unroll
            for (int c = 0; c < 2; ++c) {
                float4 v = *reinterpret_cast<const float4*>(src + c * 4);
                HL sx = split_bf16(v.x), sy = split_bf16(v.y);
                HL sz = split_bf16(v.z), sw = split_bf16(v.w);
                *reinterpret_cast<u16x4*>(Bhs + sr * LDSP + sk + c * 4) = (u16x4){sx.h, sy.h, sz.h, sw.h};
                *reinterpret_cast<u16x4*>(Bls + sr * LDSP + sk + c * 4) = (u16x4){sx.l, sy.l, sz.l, sw.l};
            }
        }
        __syncthreads();
        bf16x8 ah[2], al[2], bh[2], bl[2];
        #pragma unroll
        for (int mi = 0; mi < 2; ++mi) {
            int row = wr * 32 + mi * 16 + l15;
            ah[mi] = *reinterpret_cast<const bf16x8*>(Ahs + row * LDSP + kc);
            al[mi] = *reinterpret_cast<const bf16x8*>(Als + row * LDSP + kc);
        }
        #pragma unroll
        for (int ni = 0; ni < 2; ++ni) {
            int row = wc * 32 + ni * 16 + l15;
            bh[ni] = *reinterpret_cast<const bf16x8*>(Bhs + row * LDSP + kc);
            bl[ni] = *reinterpret_cast<const bf16x8*>(Bls + row * LDSP + kc);
        }
        #pragma unroll
        for (int mi = 0; mi < 2; ++mi)
            #pragma unroll
            for (int ni = 0; ni < 2; ++ni) {
                acc[mi][ni] = __builtin_amdgcn_mfma_f32_16x16x32_bf16(ah[mi], bh[ni], acc[mi][ni], 0, 0, 0);
                acc[mi][ni] = __builtin_amdgcn_mfma_f32_16x16x32_bf16(ah[mi], bl[ni], acc[mi][ni], 0, 0, 0);
                acc[mi][ni] = __builtin_amdgcn_mfma_f32_16x16x32_bf16(al[mi], bh[ni], acc[mi][ni], 0, 0, 0);
            }
        __syncthreads();
    }
    #pragma unroll
    for (int mi = 0; mi < 2; ++mi)
        #pragma unroll
        for (int ni = 0; ni < 2; ++ni) {
            int row0 = bm0 + wr * 32 + mi * 16 + (lane >> 4) * 4;
            int col  = bn0 + wc * 32 + ni * 16 + l15;
            #pragma unroll
            for (int r = 0; r < 4; ++r)
                D[(size_t)(row0 + r) * NCOLS + col] = acc[mi][ni][r];
        }
}

__global__ __launch_bounds__(256) void naive_kernel(
    const float* __restrict__ seq, const float* __restrict__ W,
    const float* __restrict__ bias, float* __restrict__ out)
{
    const int p = blockIdx.x;
    const int b = blockIdx.y;
    int i, j;
    tri_decode(p, L_SEQ, i, j);
    const float* si = seq + ((size_t)b * L_SEQ + i) * H_DIM;
    const float* sj = seq + ((size_t)b * L_SEQ + j) * H_DIM;
    for (int h = threadIdx.x; h < H_DIM; h += 256) {
        const float* wr = W + (size_t)h * NCOLS;
        float s = bias[h];
        for (int k = 0; k < H_DIM; ++k)
            s += si[k] * wr[k] + sj[k] * wr[H_DIM + k];
        out[((size_t)b * NPAIR + p) * H_DIM + h] = tanhf(s);
    }
}

extern "C" void kernel_launch(void* const* d_in, const int* in_sizes, int n_in,
                              void* d_out, int out_size, void* d_ws, size_t ws_size,
                              hipStream_t stream) {
    const float* seq  = (const float*)d_in[0];
    const float* W    = (const float*)d_in[1];
    const float* bias = (const float*)d_in[2];
    float* out = (float*)d_out;

    if (ws_size >= WS_NEED_FULL) {
        char* ws = (char*)d_ws;
        float* D = (float*)ws;
        unsigned short* SH = (unsigned short*)(ws + D_BYTES);
        unsigned short* SL = SH + SEQ_ELEMS;
        unsigned short* WH = SL + SEQ_ELEMS;
        unsigned short* WL = WH + W_ELEMS;

        const int nsplit4 = (SEQ_ELEMS + W_ELEMS) / 4;
        hipLaunchKernelGGL(presplit_kernel, dim3(nsplit4 / 256), dim3(256), 0, stream,
                           seq, W, SH, SL, WH, WL);
        dim3 g1(NCOLS / 128, MROWS / 128);   // 12 x 12 = 144 blocks
        hipLaunchKernelGGL(gemm_bf16_128_kernel, g1, dim3(256), 0, stream, SH, SL, WH, WL, D);
        dim3 g2(NTRI, B_SZ);                 // 300 x 8
        hipLaunchKernelGGL(combine_tile_kernel, g2, dim3(192), 0, stream, D, bias, out);
    } else if (ws_size >= D_BYTES) {
        float* D = (float*)d_ws;
        dim3 g1(NCOLS / 64, MROWS / 64);
        hipLaunchKernelGGL(gemm_mfma64_kernel, g1, dim3(256), 0, stream, seq, W, D);
        dim3 g2(NTRI, B_SZ);
        hipLaunchKernelGGL(combine_tile_kernel, g2, dim3(192), 0, stream, D, bias, out);
    } else {
        dim3 g(NPAIR, B_SZ);
        hipLaunchKernelGGL(naive_kernel, g, dim3(256), 0, stream, seq, W, bias, out);
    }
}

// Round 14
// 120.492 us; speedup vs baseline: 1.0405x; 1.0405x over previous
//
#include <hip/hip_runtime.h>
#include <math.h>

#define L_SEQ 192
#define H_DIM 768
#define B_SZ  8
#define NPAIR (L_SEQ * (L_SEQ + 1) / 2)   // 18528
#define MROWS (B_SZ * L_SEQ)              // 1536
#define NCOLS (2 * H_DIM)                 // 1536 (D columns: [A | C])
#define NTILE 24
#define NTRI  (NTILE * (NTILE + 1) / 2)    // 300

#define SEQ_ELEMS (MROWS * H_DIM)          // 1,179,648
#define W_ELEMS   (H_DIM * NCOLS)          // 1,179,648
#define D_BYTES   ((size_t)MROWS * NCOLS * 4)
#define WS_NEED_FULL (D_BYTES + 4 * (size_t)SEQ_ELEMS * 2)   // 18.9 MB

typedef short  bf16x8  __attribute__((ext_vector_type(8)));
typedef float  f32x4   __attribute__((ext_vector_type(4)));
typedef unsigned short u16x4 __attribute__((ext_vector_type(4)));
typedef unsigned short u16x8 __attribute__((ext_vector_type(8)));

__device__ __forceinline__ void tri_decode(int p, int Lq, int& io, int& jo) {
    float tl = 2.0f * Lq + 1.0f;
    int i = (int)((tl - sqrtf(tl * tl - 8.0f * (float)p)) * 0.5f);
    if (i < 0) i = 0;
    if (i > Lq - 1) i = Lq - 1;
    while (i > 0 && i * (2 * Lq - i + 1) / 2 > p) --i;
    while (i < Lq - 1 && (i + 1) * (2 * Lq - i) / 2 <= p) ++i;
    io = i;
    jo = i + (p - i * (2 * Lq - i + 1) / 2);
}

struct HL { unsigned short h, l; };

__device__ __forceinline__ HL split_bf16(float x) {
    HL r;
    unsigned u  = __float_as_uint(x);
    unsigned rh = u + 0x7FFFu + ((u >> 16) & 1u);
    r.h = (unsigned short)(rh >> 16);
    float hf = __uint_as_float((unsigned)r.h << 16);
    float res = x - hf;
    unsigned u2 = __float_as_uint(res);
    unsigned rl = u2 + 0x7FFFu + ((u2 >> 16) & 1u);
    r.l = (unsigned short)(rl >> 16);
    return r;
}

__device__ __forceinline__ float fast_tanh(float x) {
    float e = __builtin_amdgcn_exp2f(x * 2.885390081777927f);
    return 1.0f - 2.0f * __builtin_amdgcn_rcpf(e + 1.0f);
}

// ---------------------------------------------------------------------------
// Presplit: seq -> SH/SL, W -> WH/WL (hi/lo bf16), one float4 per thread.
// ~2 us (measured r7: 1.9 us/rep).
// ---------------------------------------------------------------------------
__global__ __launch_bounds__(256) void presplit_kernel(
    const float* __restrict__ seq, const float* __restrict__ W,
    unsigned short* __restrict__ SH, unsigned short* __restrict__ SL,
    unsigned short* __restrict__ WH, unsigned short* __restrict__ WL)
{
    int idx = blockIdx.x * 256 + threadIdx.x;
    const int NSEQ4 = SEQ_ELEMS / 4;
    const float4* src;
    u16x4 *dh, *dl;
    if (idx < NSEQ4) {
        src = reinterpret_cast<const float4*>(seq) + idx;
        dh = reinterpret_cast<u16x4*>(SH) + idx;
        dl = reinterpret_cast<u16x4*>(SL) + idx;
    } else {
        int k = idx - NSEQ4;
        src = reinterpret_cast<const float4*>(W) + k;
        dh = reinterpret_cast<u16x4*>(WH) + k;
        dl = reinterpret_cast<u16x4*>(WL) + k;
    }
    float4 v = *src;
    HL sx = split_bf16(v.x), sy = split_bf16(v.y);
    HL sz = split_bf16(v.z), sw = split_bf16(v.w);
    *dh = (u16x4){sx.h, sy.h, sz.h, sw.h};
    *dl = (u16x4){sx.l, sy.l, sz.l, sw.l};
}

// ---------------------------------------------------------------------------
// GEMM from pre-split bf16 (round-9 winner, ~22 us): 64x64 tiles, 576
// blocks (2.25/CU), 4 waves (2x2), each wave 32x32 via 2x2 frags of
// 16x16x32; 3 MFMAs per frag pair (hh + hl + lh). Measured optimal over:
// 128^2 tile (r13, occupancy-bound), LDS-free direct (r8, latency-bound),
// explicit double-buffer (r11, null — LDS-throughput-bound).
// ---------------------------------------------------------------------------
#define LDSP 40

__global__ __launch_bounds__(256) void gemm_bf16_kernel(
    const unsigned short* __restrict__ SH, const unsigned short* __restrict__ SL,
    const unsigned short* __restrict__ WH, const unsigned short* __restrict__ WL,
    float* __restrict__ D)
{
    __shared__ unsigned short Ah[64 * LDSP], Al[64 * LDSP];
    __shared__ unsigned short Bh[64 * LDSP], Bl[64 * LDSP];

    const int t    = threadIdx.x;
    const int bn0  = blockIdx.x * 64;
    const int bm0  = blockIdx.y * 64;
    const int side = (bn0 >= H_DIM) ? 1 : 0;
    const int wrow0 = bn0 - side * H_DIM;
    const int kofs  = side * H_DIM;

    const int lane = t & 63;
    const int wave = t >> 6;
    const int wr   = wave >> 1, wc = wave & 1;
    const int l15  = lane & 15;
    const int kc   = (lane >> 4) * 8;

    const int sr = t >> 2;
    const int sk = (t & 3) * 8;

    const unsigned short* srcA_h = SH + (size_t)(bm0 + sr) * H_DIM + sk;
    const unsigned short* srcA_l = SL + (size_t)(bm0 + sr) * H_DIM + sk;
    const unsigned short* srcB_h = WH + (size_t)(wrow0 + sr) * NCOLS + kofs + sk;
    const unsigned short* srcB_l = WL + (size_t)(wrow0 + sr) * NCOLS + kofs + sk;

    f32x4 acc[2][2];
    #pragma unroll
    for (int a = 0; a < 2; ++a)
        #pragma unroll
        for (int b = 0; b < 2; ++b) acc[a][b] = (f32x4){0.f, 0.f, 0.f, 0.f};

    u16x8 nah = *reinterpret_cast<const u16x8*>(srcA_h);
    u16x8 nal = *reinterpret_cast<const u16x8*>(srcA_l);
    u16x8 nbh = *reinterpret_cast<const u16x8*>(srcB_h);
    u16x8 nbl = *reinterpret_cast<const u16x8*>(srcB_l);

    for (int k0 = 0; k0 < H_DIM; k0 += 32) {
        const u16x8 cah = nah, cal = nal, cbh = nbh, cbl = nbl;
        if (k0 + 32 < H_DIM) {
            nah = *reinterpret_cast<const u16x8*>(srcA_h + k0 + 32);
            nal = *reinterpret_cast<const u16x8*>(srcA_l + k0 + 32);
            nbh = *reinterpret_cast<const u16x8*>(srcB_h + k0 + 32);
            nbl = *reinterpret_cast<const u16x8*>(srcB_l + k0 + 32);
        }
        *reinterpret_cast<u16x8*>(Ah + sr * LDSP + sk) = cah;
        *reinterpret_cast<u16x8*>(Al + sr * LDSP + sk) = cal;
        *reinterpret_cast<u16x8*>(Bh + sr * LDSP + sk) = cbh;
        *reinterpret_cast<u16x8*>(Bl + sr * LDSP + sk) = cbl;
        __syncthreads();

        bf16x8 ah[2], al[2], bh[2], bl[2];
        #pragma unroll
        for (int mi = 0; mi < 2; ++mi) {
            int row = wr * 32 + mi * 16 + l15;
            ah[mi] = *reinterpret_cast<const bf16x8*>(Ah + row * LDSP + kc);
            al[mi] = *reinterpret_cast<const bf16x8*>(Al + row * LDSP + kc);
        }
        #pragma unroll
        for (int ni = 0; ni < 2; ++ni) {
            int row = wc * 32 + ni * 16 + l15;
            bh[ni] = *reinterpret_cast<const bf16x8*>(Bh + row * LDSP + kc);
            bl[ni] = *reinterpret_cast<const bf16x8*>(Bl + row * LDSP + kc);
        }

        #pragma unroll
        for (int mi = 0; mi < 2; ++mi)
            #pragma unroll
            for (int ni = 0; ni < 2; ++ni) {
                acc[mi][ni] = __builtin_amdgcn_mfma_f32_16x16x32_bf16(ah[mi], bh[ni], acc[mi][ni], 0, 0, 0);
                acc[mi][ni] = __builtin_amdgcn_mfma_f32_16x16x32_bf16(ah[mi], bl[ni], acc[mi][ni], 0, 0, 0);
                acc[mi][ni] = __builtin_amdgcn_mfma_f32_16x16x32_bf16(al[mi], bh[ni], acc[mi][ni], 0, 0, 0);
            }
        __syncthreads();
    }

    #pragma unroll
    for (int mi = 0; mi < 2; ++mi)
        #pragma unroll
        for (int ni = 0; ni < 2; ++ni) {
            int row0 = bm0 + wr * 32 + mi * 16 + (lane >> 4) * 4;
            int col  = bn0 + wc * 32 + ni * 16 + l15;
            #pragma unroll
            for (int r = 0; r < 4; ++r)
                D[(size_t)(row0 + r) * NCOLS + col] = acc[mi][ni][r];
        }
}

// ---------------------------------------------------------------------------
// Tiled combine (round-9 winner, ~94 us — structural ceiling): one block =
// 8x8 (i,j) pair tile for one batch; 16 upfront independent loads, 64
// independent f32x4 store iterations, plain stores. Falsified alternatives:
// per-pair blocks (r3), NT stores (r9 A/B), thread-sequential rows (r10),
// grid-stride window (r12) — all null or worse.
// ---------------------------------------------------------------------------
__global__ __launch_bounds__(192) void combine_tile_kernel(
    const float* __restrict__ D, const float* __restrict__ bias,
    float* __restrict__ out)
{
    const int b = blockIdx.y;
    int it, jt;
    tri_decode(blockIdx.x, NTILE, it, jt);

    const int h = threadIdx.x * 4;
    const f32x4 bb = *reinterpret_cast<const f32x4*>(bias + h);
    const float* Dbase = D + (size_t)b * L_SEQ * NCOLS;

    f32x4 Ar[8], Cr[8];
    #pragma unroll
    for (int r = 0; r < 8; ++r)
        Ar[r] = *reinterpret_cast<const f32x4*>(Dbase + (size_t)(it * 8 + r) * NCOLS + h) + bb;
    #pragma unroll
    for (int r = 0; r < 8; ++r)
        Cr[r] = *reinterpret_cast<const f32x4*>(Dbase + (size_t)(jt * 8 + r) * NCOLS + H_DIM + h);

    const int diag = (it == jt);

    #pragma unroll
    for (int di = 0; di < 8; ++di) {
        const int i = it * 8 + di;
        const int prow = i * (2 * L_SEQ - i + 1) / 2 - i;   // p = prow + j
        float* orow = out + ((size_t)b * NPAIR + prow) * H_DIM + h;
        #pragma unroll
        for (int dj = 0; dj < 8; ++dj) {
            if (diag && dj < di) continue;
            const int j = jt * 8 + dj;
            f32x4 s = Ar[di] + Cr[dj];
            f32x4 o;
            o.x = fast_tanh(s.x); o.y = fast_tanh(s.y);
            o.z = fast_tanh(s.z); o.w = fast_tanh(s.w);
            *reinterpret_cast<f32x4*>(orow + (size_t)j * H_DIM) = o;
        }
    }
}

// ---------------------------------------------------------------------------
// Fallbacks (middle: in-kernel split + LDS GEMM; last: naive einsum)
// ---------------------------------------------------------------------------
__global__ __launch_bounds__(256) void gemm_mfma64_kernel(
    const float* __restrict__ seq, const float* __restrict__ W,
    float* __restrict__ D)
{
    __shared__ unsigned short Ahs[64 * LDSP], Als[64 * LDSP];
    __shared__ unsigned short Bhs[64 * LDSP], Bls[64 * LDSP];
    const int t    = threadIdx.x;
    const int bn0  = blockIdx.x * 64;
    const int bm0  = blockIdx.y * 64;
    const int side = (bn0 >= H_DIM) ? 1 : 0;
    const int wrow0 = bn0 - side * H_DIM;
    const int kofs  = side * H_DIM;
    const int lane = t & 63;
    const int wave = t >> 6;
    const int wr   = wave >> 1, wc = wave & 1;
    const int l15  = lane & 15;
    const int kc   = (lane >> 4) * 8;
    const int sr = t >> 2;
    const int sk = (t & 3) * 8;

    f32x4 acc[2][2];
    #pragma unroll
    for (int a = 0; a < 2; ++a)
        #pragma unroll
        for (int b = 0; b < 2; ++b) acc[a][b] = (f32x4){0.f, 0.f, 0.f, 0.f};

    for (int k0 = 0; k0 < H_DIM; k0 += 32) {
        {
            const float* src = seq + (size_t)(bm0 + sr) * H_DIM + k0 + sk;
            #pragma unroll
            for (int c = 0; c < 2; ++c) {
                float4 v = *reinterpret_cast<const float4*>(src + c * 4);
                HL sx = split_bf16(v.x), sy = split_bf16(v.y);
                HL sz = split_bf16(v.z), sw = split_bf16(v.w);
                *reinterpret_cast<u16x4*>(Ahs + sr * LDSP + sk + c * 4) = (u16x4){sx.h, sy.h, sz.h, sw.h};
                *reinterpret_cast<u16x4*>(Als + sr * LDSP + sk + c * 4) = (u16x4){sx.l, sy.l, sz.l, sw.l};
            }
        }
        {
            const float* src = W + (size_t)(wrow0 + sr) * NCOLS + kofs + k0 + sk;
            #pragma unroll
            for (int c = 0; c < 2; ++c) {
                float4 v = *reinterpret_cast<const float4*>(src + c * 4);
                HL sx = split_bf16(v.x), sy = split_bf16(v.y);
                HL sz = split_bf16(v.z), sw = split_bf16(v.w);
                *reinterpret_cast<u16x4*>(Bhs + sr * LDSP + sk + c * 4) = (u16x4){sx.h, sy.h, sz.h, sw.h};
                *reinterpret_cast<u16x4*>(Bls + sr * LDSP + sk + c * 4) = (u16x4){sx.l, sy.l, sz.l, sw.l};
            }
        }
        __syncthreads();
        bf16x8 ah[2], al[2], bh[2], bl[2];
        #pragma unroll
        for (int mi = 0; mi < 2; ++mi) {
            int row = wr * 32 + mi * 16 + l15;
            ah[mi] = *reinterpret_cast<const bf16x8*>(Ahs + row * LDSP + kc);
            al[mi] = *reinterpret_cast<const bf16x8*>(Als + row * LDSP + kc);
        }
        #pragma unroll
        for (int ni = 0; ni < 2; ++ni) {
            int row = wc * 32 + ni * 16 + l15;
            bh[ni] = *reinterpret_cast<const bf16x8*>(Bhs + row * LDSP + kc);
            bl[ni] = *reinterpret_cast<const bf16x8*>(Bls + row * LDSP + kc);
        }
        #pragma unroll
        for (int mi = 0; mi < 2; ++mi)
            #pragma unroll
            for (int ni = 0; ni < 2; ++ni) {
                acc[mi][ni] = __builtin_amdgcn_mfma_f32_16x16x32_bf16(ah[mi], bh[ni], acc[mi][ni], 0, 0, 0);
                acc[mi][ni] = __builtin_amdgcn_mfma_f32_16x16x32_bf16(ah[mi], bl[ni], acc[mi][ni], 0, 0, 0);
                acc[mi][ni] = __builtin_amdgcn_mfma_f32_16x16x32_bf16(al[mi], bh[ni], acc[mi][ni], 0, 0, 0);
            }
        __syncthreads();
    }
    #pragma unroll
    for (int mi = 0; mi < 2; ++mi)
        #pragma unroll
        for (int ni = 0; ni < 2; ++ni) {
            int row0 = bm0 + wr * 32 + mi * 16 + (lane >> 4) * 4;
            int col  = bn0 + wc * 32 + ni * 16 + l15;
            #pragma unroll
            for (int r = 0; r < 4; ++r)
                D[(size_t)(row0 + r) * NCOLS + col] = acc[mi][ni][r];
        }
}

__global__ __launch_bounds__(256) void naive_kernel(
    const float* __restrict__ seq, const float* __restrict__ W,
    const float* __restrict__ bias, float* __restrict__ out)
{
    const int p = blockIdx.x;
    const int b = blockIdx.y;
    int i, j;
    tri_decode(p, L_SEQ, i, j);
    const float* si = seq + ((size_t)b * L_SEQ + i) * H_DIM;
    const float* sj = seq + ((size_t)b * L_SEQ + j) * H_DIM;
    for (int h = threadIdx.x; h < H_DIM; h += 256) {
        const float* wr = W + (size_t)h * NCOLS;
        float s = bias[h];
        for (int k = 0; k < H_DIM; ++k)
            s += si[k] * wr[k] + sj[k] * wr[H_DIM + k];
        out[((size_t)b * NPAIR + p) * H_DIM + h] = tanhf(s);
    }
}

extern "C" void kernel_launch(void* const* d_in, const int* in_sizes, int n_in,
                              void* d_out, int out_size, void* d_ws, size_t ws_size,
                              hipStream_t stream) {
    const float* seq  = (const float*)d_in[0];
    const float* W    = (const float*)d_in[1];
    const float* bias = (const float*)d_in[2];
    float* out = (float*)d_out;

    if (ws_size >= WS_NEED_FULL) {
        char* ws = (char*)d_ws;
        float* D = (float*)ws;
        unsigned short* SH = (unsigned short*)(ws + D_BYTES);
        unsigned short* SL = SH + SEQ_ELEMS;
        unsigned short* WH = SL + SEQ_ELEMS;
        unsigned short* WL = WH + W_ELEMS;

        const int nsplit4 = (SEQ_ELEMS + W_ELEMS) / 4;
        hipLaunchKernelGGL(presplit_kernel, dim3(nsplit4 / 256), dim3(256), 0, stream,
                           seq, W, SH, SL, WH, WL);
        dim3 g1(NCOLS / 64, MROWS / 64);     // 24 x 24 = 576 blocks
        hipLaunchKernelGGL(gemm_bf16_kernel, g1, dim3(256), 0, stream, SH, SL, WH, WL, D);
        dim3 g2(NTRI, B_SZ);                 // 300 x 8
        hipLaunchKernelGGL(combine_tile_kernel, g2, dim3(192), 0, stream, D, bias, out);
    } else if (ws_size >= D_BYTES) {
        float* D = (float*)d_ws;
        dim3 g1(NCOLS / 64, MROWS / 64);
        hipLaunchKernelGGL(gemm_mfma64_kernel, g1, dim3(256), 0, stream, seq, W, D);
        dim3 g2(NTRI, B_SZ);
        hipLaunchKernelGGL(combine_tile_kernel, g2, dim3(192), 0, stream, D, bias, out);
    } else {
        dim3 g(NPAIR, B_SZ);
        hipLaunchKernelGGL(naive_kernel, g, dim3(256), 0, stream, seq, W, bias, out);
    }
}